// Round 3
// baseline (1181.893 us; speedup 1.0000x reference)
//
#include <hip/hip_runtime.h>
#include <cfloat>

#define PIXB 1024
static const size_t OFF_Z = 6291456;   // recon = 32*3*256*256
static const size_t OFF_E = 23068672;  // OFF_Z + 32*512*32*32
static const size_t OFF_A = 39845888;  // OFF_E + 32*512*32*32

typedef __attribute__((address_space(1))) const unsigned int cg_u32;
typedef __attribute__((address_space(3))) unsigned int l_u32;

// ---------------- encode: z_e = conv(x) + b, as GEMM 512x192 @ 192x32768 ----
// plus 2 extra blocks (blockIdx.y==8) computing w2[k] = sum_d W[d,k]^2
__global__ __launch_bounds__(256) void k_encode(const float* __restrict__ x,
                                                const float* __restrict__ ew,
                                                const float* __restrict__ eb,
                                                const float* __restrict__ emb,
                                                float* __restrict__ w2,
                                                float* __restrict__ out) {
  if (blockIdx.y == 8) {
    if (blockIdx.x < 2) {
      const int k = blockIdx.x * 256 + threadIdx.x;
      float acc = 0.f;
      for (int d = 0; d < 512; ++d) { const float v = emb[(size_t)d * 512 + k]; acc = fmaf(v, v, acc); }
      w2[k] = acc;
    }
    return;
  }
  __shared__ __align__(16) float Ps[16][68];
  __shared__ __align__(16) float Ws[16][68];
  const int n0 = blockIdx.x * 64;
  const int b = n0 / PIXB;
  const int pixbase = n0 % PIXB;
  const int i0 = pixbase >> 5;
  const int c0 = blockIdx.y * 64;
  const int t = threadIdx.x;
  const int tx = t & 15, ty = t >> 4;
  float acc[4][4];
#pragma unroll
  for (int m = 0; m < 4; ++m)
#pragma unroll
    for (int p = 0; p < 4; ++p) acc[m][p] = 0.f;

  const int jj = t >> 3, kjj = t & 7;
  for (int kc = 0; kc < 12; ++kc) {
    const int ci = kc >> 2, kip = kc & 3;
#pragma unroll
    for (int rr = 0; rr < 4; ++rr) {
      const int di = rr >> 1, dki = rr & 1;
      const int row = (i0 + di) * 8 + kip * 2 + dki;
      const float v = x[(((size_t)b * 3 + ci) * 256 + row) * 256 + t];
      Ps[dki * 8 + kjj][di * 32 + jj] = v;
    }
    const int k0 = kc * 16;
#pragma unroll
    for (int ii = 0; ii < 4; ++ii) {
      const int idx = t + ii * 256;
      const int cc = idx >> 4, kk = idx & 15;
      Ws[kk][cc] = ew[(size_t)(c0 + cc) * 192 + k0 + kk];
    }
    __syncthreads();
#pragma unroll
    for (int kk = 0; kk < 16; ++kk) {
      const float4 av = *reinterpret_cast<const float4*>(&Ws[kk][ty * 4]);
      const float4 bv = *reinterpret_cast<const float4*>(&Ps[kk][tx * 4]);
      const float a[4] = {av.x, av.y, av.z, av.w};
      const float bb[4] = {bv.x, bv.y, bv.z, bv.w};
#pragma unroll
      for (int m = 0; m < 4; ++m)
#pragma unroll
        for (int p = 0; p < 4; ++p) acc[m][p] = fmaf(a[m], bb[p], acc[m][p]);
    }
    __syncthreads();
  }
#pragma unroll
  for (int m = 0; m < 4; ++m) {
    const int c = c0 + ty * 4 + m;
    const float bias = eb[c];
    float4 v;
    v.x = acc[m][0] + bias; v.y = acc[m][1] + bias;
    v.z = acc[m][2] + bias; v.w = acc[m][3] + bias;
    *reinterpret_cast<float4*>(&out[OFF_Z + ((size_t)b * 512 + c) * 1024 + pixbase + tx * 4]) = v;
  }
}

// -------- distance + argmin + gather: per block 32 pixels x all 512 codes ----
// 8x8 microtile, global_load_lds staging, fused z2 (distributed owners)
// launch_bounds(256,2): 256-VGPR budget so the 64 accumulators stay in arch
// VGPRs (round 2's (256)+35KB-LDS made the compiler AGPR-spill them: 60 VGPR,
// 3x VALU ops via v_accvgpr_read/write).
__global__ __launch_bounds__(256, 2) void k_dist(const float* __restrict__ Wc,
                                                 const float* __restrict__ w2ws,
                                                 float* out) {
  __shared__ __align__(16) float S[16 * 512];      // W chunk [16][512] (32KB), reused for reductions
  __shared__ __align__(16) float Zs[16 * 32 + 64]; // Z chunk [16][32] + scratch
  const int t = threadIdx.x;
  const int tx = t & 3;          // pixel octet: pixels tx*8 .. tx*8+7
  const int ty = t >> 2;         // code quad 0..63: codes ty*4..+3 and 256+ty*4..+3
  const int w  = t >> 6;         // wave id
  const int lane = t & 63;
  const int n0 = blockIdx.x * 32;
  const int b = n0 >> 10;
  const int pixbase = n0 & 1023;

  float acc[8][8];
#pragma unroll
  for (int p = 0; p < 8; ++p)
#pragma unroll
    for (int c = 0; c < 8; ++c) acc[p][c] = 0.f;
  float z2part[8];
#pragma unroll
  for (int p = 0; p < 8; ++p) z2part[p] = 0.f;

  // hoisted per-lane staging bases; advance by constant stride per chunk
  const float* wsrc = Wc + (size_t)(w * 4) * 512 + lane * 4;          // + i-offsets below
  const float* zsrc = out + OFF_Z + ((size_t)(b * 512 + w * 8 + (lane >> 3))) * 1024 + pixbase + (lane & 7) * 4;

  for (int ch = 0; ch < 32; ++ch) {
    // stage W: 16 rows x 512 codes; 32 1KB-segments, 8 per wave
#pragma unroll
    for (int i = 0; i < 8; ++i) {
      const int r = w * 4 + (i >> 1);
      const int half = i & 1;
      __builtin_amdgcn_global_load_lds((cg_u32*)(wsrc + (i >> 1) * 512 + half * 256),
                                       (l_u32*)&S[r * 512 + half * 256], 16, 0, 0);
    }
    // stage z: 16 rows x 32 pix = 2KB, waves 0,1
    if (w < 2) {
      __builtin_amdgcn_global_load_lds((cg_u32*)zsrc, (l_u32*)&Zs[w * 256], 16, 0, 0);
    }
    wsrc += 16 * 512;
    zsrc += 16 * 1024;
    __syncthreads();
    const int cHi = ch >> 3;
#pragma unroll
    for (int dd = 0; dd < 16; ++dd) {
      const float4 zv0 = *reinterpret_cast<const float4*>(&Zs[dd * 32 + tx * 8]);
      const float4 zv1 = *reinterpret_cast<const float4*>(&Zs[dd * 32 + tx * 8 + 4]);
      const float4 wv0 = *reinterpret_cast<const float4*>(&S[dd * 512 + ty * 4]);
      const float4 wv1 = *reinterpret_cast<const float4*>(&S[dd * 512 + 256 + ty * 4]);
      const float z[8]  = {zv0.x, zv0.y, zv0.z, zv0.w, zv1.x, zv1.y, zv1.z, zv1.w};
      const float wv[8] = {wv0.x, wv0.y, wv0.z, wv0.w, wv1.x, wv1.y, wv1.z, wv1.w};
#pragma unroll
      for (int p = 0; p < 8; ++p)
#pragma unroll
        for (int c = 0; c < 8; ++c) acc[p][c] = fmaf(z[p], wv[c], acc[p][c]);
      if (ty == dd * 4 + cHi) {   // distributed z2 ownership: d = ch*16+dd
#pragma unroll
        for (int p = 0; p < 8; ++p) z2part[p] = fmaf(z[p], z[p], z2part[p]);
      }
    }
    __syncthreads();
  }

  // ---- z2 reduce over the 64 ty owners (deterministic order) ----
#pragma unroll
  for (int p = 0; p < 8; ++p) S[4096 + ty * 36 + tx * 8 + p] = z2part[p];
  __syncthreads();
  if (t < 32) {
    float s = 0.f;
    for (int y = 0; y < 64; ++y) s += S[4096 + y * 36 + t];
    Zs[512 + t] = s;
  }
  __syncthreads();
  float z2r[8];
#pragma unroll
  for (int p = 0; p < 8; ++p) z2r[p] = Zs[512 + tx * 8 + p];

  // ---- d2 + per-thread argmin (ref rounding: (z2 - 2*zw) + w2) ----
  float bestv[8]; int besti[8];
#pragma unroll
  for (int p = 0; p < 8; ++p) { bestv[p] = FLT_MAX; besti[p] = 0x7fffffff; }
#pragma unroll
  for (int c = 0; c < 8; ++c) {
    const int code = (c < 4) ? (ty * 4 + c) : (256 + ty * 4 + (c - 4));
    const float w2v = w2ws[code];
#pragma unroll
    for (int p = 0; p < 8; ++p) {
      const float s1 = z2r[p] - 2.0f * acc[p][c];
      const float d2v = s1 + w2v;
      if (d2v < bestv[p] || (d2v == bestv[p] && code < besti[p])) { bestv[p] = d2v; besti[p] = code; }
    }
  }

  // ---- cross-thread argmin reduce (64 ty per pixel), first-index tie-break ----
  int* ri = reinterpret_cast<int*>(&S[4096]);
#pragma unroll
  for (int p = 0; p < 8; ++p) { S[ty * 36 + tx * 8 + p] = bestv[p]; ri[2304 + ty * 36 + tx * 8 + p] = besti[p]; }
  __syncthreads();
  if (t < 32) {
    float bv = S[t]; int bi = ri[2304 + t];
    for (int y = 1; y < 64; ++y) {
      const float v = S[y * 36 + t]; const int ii = ri[2304 + y * 36 + t];
      if (v < bv || (v == bv && ii < bi)) { bv = v; bi = ii; }
    }
    out[OFF_A + n0 + t] = (float)bi;
    reinterpret_cast<int*>(&Zs[544])[t] = bi;
  }
  __syncthreads();

  // ---- gather emb ----
  const int pix = t & 31;
  const int kidx = reinterpret_cast<int*>(&Zs[544])[pix];
  for (int d = t >> 5; d < 512; d += 8)
    out[OFF_E + ((size_t)(b * 512 + d)) * 1024 + pixbase + pix] = Wc[(size_t)d * 512 + kidx];
}

// ---------------- decode: conv_transpose (kernel spatially FLIPPED) ---------
__global__ __launch_bounds__(256) void k_decode(const float* __restrict__ dw,
                                                const float* __restrict__ db,
                                                float* out) {
  __shared__ __align__(16) float Qs[32][132];
  __shared__ __align__(16) float Ws3[32][68];
  const int n0 = blockIdx.x * 128;
  const int b = n0 / PIXB, pixbase = n0 % PIXB;
  const int mt = blockIdx.y;
  const int t = threadIdx.x;
  const int pg = t & 31, ck = t >> 5;
  float acc[4][8];
#pragma unroll
  for (int p = 0; p < 4; ++p)
#pragma unroll
    for (int k = 0; k < 8; ++k) acc[p][k] = 0.f;
  for (int dc = 0; dc < 16; ++dc) {
#pragma unroll
    for (int ii = 0; ii < 4; ++ii) {
      const int id = t + ii * 256;
      const int dd = id >> 5, p4 = id & 31;
      *reinterpret_cast<float4*>(&Qs[dd][p4 * 4]) =
        *reinterpret_cast<const float4*>(&out[OFF_E + ((size_t)b * 512 + dc * 32 + dd) * 1024 + pixbase + p4 * 4]);
    }
#pragma unroll
    for (int ii = 0; ii < 2; ++ii) {
      const int id = t + ii * 256;
      const int dd = id >> 4, m4 = id & 15;
      *reinterpret_cast<float4*>(&Ws3[dd][m4 * 4]) =
        *reinterpret_cast<const float4*>(&dw[(size_t)(dc * 32 + dd) * 192 + mt * 64 + m4 * 4]);
    }
    __syncthreads();
#pragma unroll
    for (int dd = 0; dd < 32; ++dd) {
      const float4 qv = *reinterpret_cast<const float4*>(&Qs[dd][pg * 4]);
      const float4 wa = *reinterpret_cast<const float4*>(&Ws3[dd][ck * 8]);
      const float4 wb = *reinterpret_cast<const float4*>(&Ws3[dd][ck * 8 + 4]);
      const float q[4] = {qv.x, qv.y, qv.z, qv.w};
      const float w[8] = {wa.x, wa.y, wa.z, wa.w, wb.x, wb.y, wb.z, wb.w};
#pragma unroll
      for (int p = 0; p < 4; ++p)
#pragma unroll
        for (int k = 0; k < 8; ++k) acc[p][k] = fmaf(q[p], w[k], acc[p][k]);
    }
    __syncthreads();
  }
  const int ckg = mt * 8 + ck;
  const int c = ckg >> 3, ki = ckg & 7;
  const float bias = db[c];
#pragma unroll
  for (int p = 0; p < 4; ++p) {
    const int pix = pixbase + pg * 4 + p;
    const int i = pix >> 5, j = pix & 31;
    const size_t base = (((size_t)b * 3 + c) * 256 + i * 8 + 7 - ki) * 256 + j * 8;
#pragma unroll
    for (int kj = 0; kj < 8; ++kj) out[base + 7 - kj] = acc[p][kj] + bias;
  }
}

extern "C" void kernel_launch(void* const* d_in, const int* in_sizes, int n_in,
                              void* d_out, int out_size, void* d_ws, size_t ws_size,
                              hipStream_t stream) {
  const float* x     = (const float*)d_in[0];
  const float* enc_w = (const float*)d_in[1];
  const float* enc_b = (const float*)d_in[2];
  const float* dec_w = (const float*)d_in[3];
  const float* dec_b = (const float*)d_in[4];
  const float* emb_w = (const float*)d_in[5];
  float* out = (float*)d_out;
  float* w2 = (float*)d_ws;          // 512 floats

  k_encode<<<dim3(512, 9), 256, 0, stream>>>(x, enc_w, enc_b, emb_w, w2, out);
  k_dist<<<1024, 256, 0, stream>>>(emb_w, w2, out);
  k_decode<<<dim3(256, 3), 256, 0, stream>>>(dec_w, dec_b, out);
}

// Round 4
// 500.003 us; speedup vs baseline: 2.3638x; 2.3638x over previous
//
#include <hip/hip_runtime.h>
#include <cfloat>

#define PIXB 1024
static const size_t OFF_Z = 6291456;   // recon = 32*3*256*256
static const size_t OFF_E = 23068672;  // OFF_Z + 32*512*32*32
static const size_t OFF_A = 39845888;  // OFF_E + 32*512*32*32

typedef __attribute__((address_space(1))) const unsigned int cg_u32;
typedef __attribute__((address_space(3))) unsigned int l_u32;

// ---------------- encode: z_e = conv(x) + b, as GEMM 512x192 @ 192x32768 ----
// plus 2 extra blocks (blockIdx.y==8) computing w2[k] = sum_d W[d,k]^2
__global__ __launch_bounds__(256) void k_encode(const float* __restrict__ x,
                                                const float* __restrict__ ew,
                                                const float* __restrict__ eb,
                                                const float* __restrict__ emb,
                                                float* __restrict__ w2,
                                                float* __restrict__ out) {
  if (blockIdx.y == 8) {
    if (blockIdx.x < 2) {
      const int k = blockIdx.x * 256 + threadIdx.x;
      float acc = 0.f;
      for (int d = 0; d < 512; ++d) { const float v = emb[(size_t)d * 512 + k]; acc = fmaf(v, v, acc); }
      w2[k] = acc;
    }
    return;
  }
  __shared__ __align__(16) float Ps[16][68];
  __shared__ __align__(16) float Ws[16][68];
  const int n0 = blockIdx.x * 64;
  const int b = n0 / PIXB;
  const int pixbase = n0 % PIXB;
  const int i0 = pixbase >> 5;
  const int c0 = blockIdx.y * 64;
  const int t = threadIdx.x;
  const int tx = t & 15, ty = t >> 4;
  float acc[4][4];
#pragma unroll
  for (int m = 0; m < 4; ++m)
#pragma unroll
    for (int p = 0; p < 4; ++p) acc[m][p] = 0.f;

  const int jj = t >> 3, kjj = t & 7;
  for (int kc = 0; kc < 12; ++kc) {
    const int ci = kc >> 2, kip = kc & 3;
#pragma unroll
    for (int rr = 0; rr < 4; ++rr) {
      const int di = rr >> 1, dki = rr & 1;
      const int row = (i0 + di) * 8 + kip * 2 + dki;
      const float v = x[(((size_t)b * 3 + ci) * 256 + row) * 256 + t];
      Ps[dki * 8 + kjj][di * 32 + jj] = v;
    }
    const int k0 = kc * 16;
#pragma unroll
    for (int ii = 0; ii < 4; ++ii) {
      const int idx = t + ii * 256;
      const int cc = idx >> 4, kk = idx & 15;
      Ws[kk][cc] = ew[(size_t)(c0 + cc) * 192 + k0 + kk];
    }
    __syncthreads();
#pragma unroll
    for (int kk = 0; kk < 16; ++kk) {
      const float4 av = *reinterpret_cast<const float4*>(&Ws[kk][ty * 4]);
      const float4 bv = *reinterpret_cast<const float4*>(&Ps[kk][tx * 4]);
      const float a[4] = {av.x, av.y, av.z, av.w};
      const float bb[4] = {bv.x, bv.y, bv.z, bv.w};
#pragma unroll
      for (int m = 0; m < 4; ++m)
#pragma unroll
        for (int p = 0; p < 4; ++p) acc[m][p] = fmaf(a[m], bb[p], acc[m][p]);
    }
    __syncthreads();
  }
#pragma unroll
  for (int m = 0; m < 4; ++m) {
    const int c = c0 + ty * 4 + m;
    const float bias = eb[c];
    float4 v;
    v.x = acc[m][0] + bias; v.y = acc[m][1] + bias;
    v.z = acc[m][2] + bias; v.w = acc[m][3] + bias;
    *reinterpret_cast<float4*>(&out[OFF_Z + ((size_t)b * 512 + c) * 1024 + pixbase + tx * 4]) = v;
  }
}

// -------- distance + argmin + gather: per block 32 pixels x all 512 codes ----
// 8x4 microtile, TWO code passes (0..255, 256..511) so true VGPR demand < 128
// (round 2: 8x8 tile = 64 acc -> compiler split 60 arch + AGPR shuffle, 2.1x
// VALU; round 3: launch_bounds(256,2) -> scratch spill, 2.7GB writes).
// global_load_lds staging; z2 fused with distributed owners (order-identical
// to the round-2 passing kernel, so argmin is bit-identical).
__global__ __launch_bounds__(256) void k_dist(const float* __restrict__ Wc,
                                              const float* __restrict__ w2ws,
                                              float* out) {
  __shared__ __align__(16) float S[4608];   // W chunk [16][256] (16KB); reduce scratch (18KB)
  __shared__ __align__(16) float Zs[576];   // z chunk [16][32] + z2[32] + idx[32]
  const int t = threadIdx.x;
  const int tx = t & 3;          // pixel octet: pixels tx*8 .. tx*8+7
  const int ty = t >> 2;         // code quad 0..63 within the current 256-code pass
  const int w  = t >> 6;         // wave id
  const int lane = t & 63;
  const int n0 = blockIdx.x * 32;
  const int b = n0 >> 10;
  const int pixbase = n0 & 1023;

  float z2part[8], z2r[8];
  float bestv[8]; int besti[8];
#pragma unroll
  for (int p = 0; p < 8; ++p) {
    z2part[p] = 0.f; bestv[p] = FLT_MAX; besti[p] = 0x7fffffff;
  }

#pragma unroll 1
  for (int cp = 0; cp < 2; ++cp) {
    const int cbase = cp * 256;
    float acc[8][4];
#pragma unroll
    for (int p = 0; p < 8; ++p)
#pragma unroll
      for (int c = 0; c < 4; ++c) acc[p][c] = 0.f;

    const float* wsrc = Wc + (size_t)(w * 4) * 512 + cbase + lane * 4;
    const float* zsrc = out + OFF_Z + ((size_t)(b * 512 + w * 8 + (lane >> 3))) * 1024 + pixbase + (lane & 7) * 4;

#pragma unroll 1
    for (int ch = 0; ch < 32; ++ch) {
      // stage W: 16 rows x 256 codes = 16KB; 4 rows (1KB segments) per wave
#pragma unroll
      for (int i = 0; i < 4; ++i)
        __builtin_amdgcn_global_load_lds((cg_u32*)(wsrc + (size_t)i * 512),
                                         (l_u32*)&S[(w * 4 + i) * 256], 16, 0, 0);
      // stage z: 16 rows x 32 pix = 2KB, waves 0,1
      if (w < 2)
        __builtin_amdgcn_global_load_lds((cg_u32*)zsrc, (l_u32*)&Zs[w * 256], 16, 0, 0);
      wsrc += 16 * 512;
      zsrc += 16 * 1024;
      __syncthreads();
      const int cHi = ch >> 3;
#pragma unroll
      for (int dd = 0; dd < 16; ++dd) {
        const float4 zv0 = *reinterpret_cast<const float4*>(&Zs[dd * 32 + tx * 8]);
        const float4 zv1 = *reinterpret_cast<const float4*>(&Zs[dd * 32 + tx * 8 + 4]);
        const float4 wv0 = *reinterpret_cast<const float4*>(&S[dd * 256 + ty * 4]);
        const float z[8]  = {zv0.x, zv0.y, zv0.z, zv0.w, zv1.x, zv1.y, zv1.z, zv1.w};
        const float wv[4] = {wv0.x, wv0.y, wv0.z, wv0.w};
#pragma unroll
        for (int p = 0; p < 8; ++p)
#pragma unroll
          for (int c = 0; c < 4; ++c) acc[p][c] = fmaf(z[p], wv[c], acc[p][c]);
        if (cp == 0 && ty == dd * 4 + cHi) {   // distributed z2 ownership: d = ch*16+dd
#pragma unroll
          for (int p = 0; p < 8; ++p) z2part[p] = fmaf(z[p], z[p], z2part[p]);
        }
      }
      __syncthreads();
    }

    if (cp == 0) {
      // ---- z2 reduce over the 64 ty owners (deterministic order); S is free ----
#pragma unroll
      for (int p = 0; p < 8; ++p) S[ty * 36 + tx * 8 + p] = z2part[p];
      __syncthreads();
      if (t < 32) {
        float s = 0.f;
        for (int y = 0; y < 64; ++y) s += S[y * 36 + t];
        Zs[512 + t] = s;
      }
      __syncthreads();
#pragma unroll
      for (int p = 0; p < 8; ++p) z2r[p] = Zs[512 + tx * 8 + p];
      __syncthreads();   // S reused by pass-1 staging right after
    }

    // ---- d2 + per-thread argmin for this pass (ref rounding: (z2-2*zw)+w2) ----
#pragma unroll
    for (int c = 0; c < 4; ++c) {
      const int code = cbase + ty * 4 + c;
      const float w2v = w2ws[code];
#pragma unroll
      for (int p = 0; p < 8; ++p) {
        const float s1 = z2r[p] - 2.0f * acc[p][c];
        const float d2v = s1 + w2v;
        if (d2v < bestv[p] || (d2v == bestv[p] && code < besti[p])) { bestv[p] = d2v; besti[p] = code; }
      }
    }
  }

  // ---- cross-thread argmin reduce (64 ty per pixel), first-index tie-break ----
  __syncthreads();
  int* ri = reinterpret_cast<int*>(&S[2304]);
#pragma unroll
  for (int p = 0; p < 8; ++p) { S[ty * 36 + tx * 8 + p] = bestv[p]; ri[ty * 36 + tx * 8 + p] = besti[p]; }
  __syncthreads();
  if (t < 32) {
    float bv = S[t]; int bi = ri[t];
    for (int y = 1; y < 64; ++y) {
      const float v = S[y * 36 + t]; const int ii = ri[y * 36 + t];
      if (v < bv || (v == bv && ii < bi)) { bv = v; bi = ii; }
    }
    out[OFF_A + n0 + t] = (float)bi;
    reinterpret_cast<int*>(&Zs[544])[t] = bi;
  }
  __syncthreads();

  // ---- gather emb ----
  const int pix = t & 31;
  const int kidx = reinterpret_cast<int*>(&Zs[544])[pix];
  for (int d = t >> 5; d < 512; d += 8)
    out[OFF_E + ((size_t)(b * 512 + d)) * 1024 + pixbase + pix] = Wc[(size_t)d * 512 + kidx];
}

// ---------------- decode: conv_transpose (kernel spatially FLIPPED) ---------
__global__ __launch_bounds__(256) void k_decode(const float* __restrict__ dw,
                                                const float* __restrict__ db,
                                                float* out) {
  __shared__ __align__(16) float Qs[32][132];
  __shared__ __align__(16) float Ws3[32][68];
  const int n0 = blockIdx.x * 128;
  const int b = n0 / PIXB, pixbase = n0 % PIXB;
  const int mt = blockIdx.y;
  const int t = threadIdx.x;
  const int pg = t & 31, ck = t >> 5;
  float acc[4][8];
#pragma unroll
  for (int p = 0; p < 4; ++p)
#pragma unroll
    for (int k = 0; k < 8; ++k) acc[p][k] = 0.f;
  for (int dc = 0; dc < 16; ++dc) {
#pragma unroll
    for (int ii = 0; ii < 4; ++ii) {
      const int id = t + ii * 256;
      const int dd = id >> 5, p4 = id & 31;
      *reinterpret_cast<float4*>(&Qs[dd][p4 * 4]) =
        *reinterpret_cast<const float4*>(&out[OFF_E + ((size_t)b * 512 + dc * 32 + dd) * 1024 + pixbase + p4 * 4]);
    }
#pragma unroll
    for (int ii = 0; ii < 2; ++ii) {
      const int id = t + ii * 256;
      const int dd = id >> 4, m4 = id & 15;
      *reinterpret_cast<float4*>(&Ws3[dd][m4 * 4]) =
        *reinterpret_cast<const float4*>(&dw[(size_t)(dc * 32 + dd) * 192 + mt * 64 + m4 * 4]);
    }
    __syncthreads();
#pragma unroll
    for (int dd = 0; dd < 32; ++dd) {
      const float4 qv = *reinterpret_cast<const float4*>(&Qs[dd][pg * 4]);
      const float4 wa = *reinterpret_cast<const float4*>(&Ws3[dd][ck * 8]);
      const float4 wb = *reinterpret_cast<const float4*>(&Ws3[dd][ck * 8 + 4]);
      const float q[4] = {qv.x, qv.y, qv.z, qv.w};
      const float w[8] = {wa.x, wa.y, wa.z, wa.w, wb.x, wb.y, wb.z, wb.w};
#pragma unroll
      for (int p = 0; p < 4; ++p)
#pragma unroll
        for (int k = 0; k < 8; ++k) acc[p][k] = fmaf(q[p], w[k], acc[p][k]);
    }
    __syncthreads();
  }
  const int ckg = mt * 8 + ck;
  const int c = ckg >> 3, ki = ckg & 7;
  const float bias = db[c];
#pragma unroll
  for (int p = 0; p < 4; ++p) {
    const int pix = pixbase + pg * 4 + p;
    const int i = pix >> 5, j = pix & 31;
    const size_t base = (((size_t)b * 3 + c) * 256 + i * 8 + 7 - ki) * 256 + j * 8;
#pragma unroll
    for (int kj = 0; kj < 8; ++kj) out[base + 7 - kj] = acc[p][kj] + bias;
  }
}

extern "C" void kernel_launch(void* const* d_in, const int* in_sizes, int n_in,
                              void* d_out, int out_size, void* d_ws, size_t ws_size,
                              hipStream_t stream) {
  const float* x     = (const float*)d_in[0];
  const float* enc_w = (const float*)d_in[1];
  const float* enc_b = (const float*)d_in[2];
  const float* dec_w = (const float*)d_in[3];
  const float* dec_b = (const float*)d_in[4];
  const float* emb_w = (const float*)d_in[5];
  float* out = (float*)d_out;
  float* w2 = (float*)d_ws;          // 512 floats

  k_encode<<<dim3(512, 9), 256, 0, stream>>>(x, enc_w, enc_b, emb_w, w2, out);
  k_dist<<<1024, 256, 0, stream>>>(emb_w, w2, out);
  k_decode<<<dim3(256, 3), 256, 0, stream>>>(dec_w, dec_b, out);
}

// Round 5
// 309.151 us; speedup vs baseline: 3.8230x; 1.6173x over previous
//
#include <hip/hip_runtime.h>
#include <cfloat>

#define PIXB 1024
static const size_t OFF_Z = 6291456;   // recon = 32*3*256*256
static const size_t OFF_E = 23068672;  // OFF_Z + 32*512*32*32
static const size_t OFF_A = 39845888;  // OFF_E + 32*512*32*32

typedef __attribute__((address_space(1))) const unsigned int cg_u32;
typedef __attribute__((address_space(3))) unsigned int l_u32;
typedef _Float16 f16x8 __attribute__((ext_vector_type(8)));
typedef float f32x16 __attribute__((ext_vector_type(16)));

#define SPLIT_SCALE 4096.0f
#define SPLIT_INV   (1.0f / 4096.0f)

// ---------------- prep: split emb_w into staged fp16 layout + w2 ------------
// Wq layout (per split s): [ch 16][code 512][40] fp16, rows padded 32->40
// (80B, 16B-aligned, conflict-free b128 column reads). Wq lives in the RECON
// region of d_out (1.31MB << 25MB), overwritten later by k_decode.
__global__ __launch_bounds__(256) void k_prep(const float* __restrict__ W,
                                              _Float16* __restrict__ wq,
                                              float* __restrict__ w2) {
  const int bx = blockIdx.x, t = threadIdx.x;
  if (bx >= 1280) {             // w2: 2 blocks
    const int k = (bx - 1280) * 256 + t;
    float acc = 0.f;
    for (int d = 0; d < 512; ++d) { const float v = W[(size_t)d * 512 + k]; acc = fmaf(v, v, acc); }
    w2[k] = acc;
    return;
  }
  const int idx = bx * 256 + t;           // 327680 positions per split
  const int j = idx % 40;
  const int c = (idx / 40) & 511;
  const int ch = idx / 20480;
  _Float16 h = (_Float16)0.f, l = (_Float16)0.f;
  if (j < 32) {
    const float v = W[(size_t)(ch * 32 + j) * 512 + c];
    h = (_Float16)v;
    l = (_Float16)((v - (float)h) * SPLIT_SCALE);
  }
  wq[idx] = h;
  wq[327680 + idx] = l;
}

// ---------------- encode: z_e = conv(x) + b, as GEMM 512x192 @ 192x32768 ----
__global__ __launch_bounds__(256) void k_encode(const float* __restrict__ x,
                                                const float* __restrict__ ew,
                                                const float* __restrict__ eb,
                                                float* __restrict__ out) {
  __shared__ __align__(16) float Ps[16][68];
  __shared__ __align__(16) float Ws[16][68];
  const int n0 = blockIdx.x * 64;
  const int b = n0 / PIXB;
  const int pixbase = n0 % PIXB;
  const int i0 = pixbase >> 5;
  const int c0 = blockIdx.y * 64;
  const int t = threadIdx.x;
  const int tx = t & 15, ty = t >> 4;
  float acc[4][4];
#pragma unroll
  for (int m = 0; m < 4; ++m)
#pragma unroll
    for (int p = 0; p < 4; ++p) acc[m][p] = 0.f;

  const int jj = t >> 3, kjj = t & 7;
  for (int kc = 0; kc < 12; ++kc) {
    const int ci = kc >> 2, kip = kc & 3;
#pragma unroll
    for (int rr = 0; rr < 4; ++rr) {
      const int di = rr >> 1, dki = rr & 1;
      const int row = (i0 + di) * 8 + kip * 2 + dki;
      const float v = x[(((size_t)b * 3 + ci) * 256 + row) * 256 + t];
      Ps[dki * 8 + kjj][di * 32 + jj] = v;
    }
    const int k0 = kc * 16;
#pragma unroll
    for (int ii = 0; ii < 4; ++ii) {
      const int idx = t + ii * 256;
      const int cc = idx >> 4, kk = idx & 15;
      Ws[kk][cc] = ew[(size_t)(c0 + cc) * 192 + k0 + kk];
    }
    __syncthreads();
#pragma unroll
    for (int kk = 0; kk < 16; ++kk) {
      const float4 av = *reinterpret_cast<const float4*>(&Ws[kk][ty * 4]);
      const float4 bv = *reinterpret_cast<const float4*>(&Ps[kk][tx * 4]);
      const float a[4] = {av.x, av.y, av.z, av.w};
      const float bb[4] = {bv.x, bv.y, bv.z, bv.w};
#pragma unroll
      for (int m = 0; m < 4; ++m)
#pragma unroll
        for (int p = 0; p < 4; ++p) acc[m][p] = fmaf(a[m], bb[p], acc[m][p]);
    }
    __syncthreads();
  }
#pragma unroll
  for (int m = 0; m < 4; ++m) {
    const int c = c0 + ty * 4 + m;
    const float bias = eb[c];
    float4 v;
    v.x = acc[m][0] + bias; v.y = acc[m][1] + bias;
    v.z = acc[m][2] + bias; v.w = acc[m][3] + bias;
    *reinterpret_cast<float4*>(&out[OFF_Z + ((size_t)b * 512 + c) * 1024 + pixbase + tx * 4]) = v;
  }
}

// -------- distance + argmin + gather via MFMA (fp16 2-split, 3 products) ----
// Block: 64 pixels x 512 codes, 512 threads (8 waves = 4 code-waves x 2 pix).
// Wave: 4 code-tiles of 32 (A operand = W^T splits), 1 pixel-tile of 32
// (B operand = z splits, transposed into LDS on the fly). 32x32x16 f16 MFMA.
// accA = zh*wh; accB = zh*wl' + zl'*wh (scaled 2^12); zw = accA + accB/4096.
// d2 = (z2 - 2*zw) + w2 in fp32, argmin with order-independent min-index
// predicate. z2 fused (deterministic fixed-order reduction). Gather uses
// exact fp32 W.
__global__ __launch_bounds__(512, 2) void k_dist(const float* __restrict__ Wc,
                                                 const float* __restrict__ w2ws,
                                                 const _Float16* wq,
                                                 float* out) {
  // LDS carve (bytes)
  //  WS : [2][512][40] f16  = 81920
  //  ZS : [2][ 64][40] f16  = 10240
  //  Z2P: [32][68] f32      =  8704
  //  W2L: [512] f32         =  2048
  //  WV : [512] f32         =  2048
  //  WI : [512] i32         =  2048
  //  Z2S: [64] f32          =   256
  //  IDX: [64] i32          =   256
  __shared__ __align__(16) unsigned char LB[107520];
  const int WS = 0, ZS = 81920, Z2P = 92160, W2L = 100864, WV = 102912,
            WI = 104960, Z2S = 107008, IDX = 107264;

  const int t = threadIdx.x;
  const int w = t >> 6, lane = t & 63;
  const int wc = w & 3;          // code-wave: codes wc*128 .. +127
  const int wp = w >> 2;         // pixel-wave: pixels wp*32 .. +31
  const int n0 = blockIdx.x * 64;
  const int b = n0 >> 10;
  const int pixbase = n0 & 1023;

  // preload w2 into LDS
  ((float*)(LB + W2L))[t] = w2ws[t];

  f32x16 accA[4], accB[4];
#pragma unroll
  for (int ct = 0; ct < 4; ++ct) { accA[ct] = (f32x16)(0.0f); accB[ct] = (f32x16)(0.0f); }
  float z2part[4];
#pragma unroll
  for (int j = 0; j < 4; ++j) z2part[j] = 0.f;

  const int dl = t >> 4;          // 0..31: d-row within chunk (z staging)
  const int pixq = t & 15;        // pixel quad
  const int klane = (lane >> 5) << 4;         // 0 or 16 bytes: k-group offset
  const int pixrow = (wp * 32 + (lane & 31)) * 80;  // B-frag row byte offset

#pragma unroll 1
  for (int ch = 0; ch < 16; ++ch) {
    __syncthreads();
    // ---- stage W chunk: 2 splits x 512 codes x 40 f16 = 80KB, linear ----
#pragma unroll
    for (int s = 0; s < 2; ++s) {
      const _Float16* gb = wq + (size_t)(s * 16 + ch) * 20480;
      for (int sg = w; sg < 40; sg += 8)
        __builtin_amdgcn_global_load_lds((cg_u32*)((const char*)gb + sg * 1024 + lane * 16),
                                         (l_u32*)(LB + WS + s * 40960 + sg * 1024), 16, 0, 0);
    }
    // ---- stage z chunk: read fp32 [32 d][64 pix], split, transpose to LDS ----
    {
      const float4 v = *reinterpret_cast<const float4*>(
          &out[OFF_Z + ((size_t)(b * 512 + ch * 32 + dl)) * 1024 + pixbase + pixq * 4]);
      const float vv[4] = {v.x, v.y, v.z, v.w};
#pragma unroll
      for (int j = 0; j < 4; ++j) {
        const float f = vv[j];
        const _Float16 zh = (_Float16)f;
        const _Float16 zl = (_Float16)((f - (float)zh) * SPLIT_SCALE);
        const int pix = pixq * 4 + j;
        *(_Float16*)(LB + ZS + pix * 80 + dl * 2) = zh;
        *(_Float16*)(LB + ZS + 5120 + pix * 80 + dl * 2) = zl;
        z2part[j] = fmaf(f, f, z2part[j]);
      }
    }
    __syncthreads();
    // ---- 2 MFMA k-steps of 16 ----
#pragma unroll
    for (int ks = 0; ks < 2; ++ks) {
      const int koff = ks * 32 + klane;
      const f16x8 Bh = *(const f16x8*)(LB + ZS + pixrow + koff);
      const f16x8 Bl = *(const f16x8*)(LB + ZS + 5120 + pixrow + koff);
#pragma unroll
      for (int ct = 0; ct < 4; ++ct) {
        const int crow = (wc * 128 + ct * 32 + (lane & 31)) * 80;
        const f16x8 Ah = *(const f16x8*)(LB + WS + crow + koff);
        const f16x8 Al = *(const f16x8*)(LB + WS + 40960 + crow + koff);
        accA[ct] = __builtin_amdgcn_mfma_f32_32x32x16_f16(Ah, Bh, accA[ct], 0, 0, 0);
        accB[ct] = __builtin_amdgcn_mfma_f32_32x32x16_f16(Ah, Bl, accB[ct], 0, 0, 0);
        accB[ct] = __builtin_amdgcn_mfma_f32_32x32x16_f16(Al, Bh, accB[ct], 0, 0, 0);
      }
    }
  }

  // ---- z2 reduce (fixed order: ascending owner) ----
  __syncthreads();
  float* z2p = (float*)(LB + Z2P);
#pragma unroll
  for (int j = 0; j < 4; ++j) z2p[(t >> 4) * 68 + (t & 15) * 4 + j] = z2part[j];
  __syncthreads();
  if (t < 64) {
    float s = 0.f;
    for (int y = 0; y < 32; ++y) s += z2p[y * 68 + t];
    ((float*)(LB + Z2S))[t] = s;
  }
  __syncthreads();

  // ---- per-lane d2 + argmin over its 128 codes ----
  // C/D layout (32x32): col = lane&31 (pixel), row = (r&3)+8*(r>>2)+4*(lane>>5)
  const float z2v = ((float*)(LB + Z2S))[wp * 32 + (lane & 31)];
  const float* w2L = (const float*)(LB + W2L);
  float bv = FLT_MAX; int bi = 0x7fffffff;
#pragma unroll
  for (int ct = 0; ct < 4; ++ct) {
#pragma unroll
    for (int r = 0; r < 16; ++r) {
      const int code = wc * 128 + ct * 32 + ((r & 3) + ((r >> 2) << 3) + ((lane >> 5) << 2));
      const float zw = fmaf(accB[ct][r], SPLIT_INV, accA[ct][r]);
      const float d2 = fmaf(-2.f, zw, z2v) + w2L[code];
      if (d2 < bv || (d2 == bv && code < bi)) { bv = d2; bi = code; }
    }
  }
  ((float*)(LB + WV))[w * 64 + lane] = bv;
  ((int*)(LB + WI))[w * 64 + lane] = bi;
  __syncthreads();

  // ---- final per-pixel reduce (8 candidates), write argmin ----
  if (t < 64) {
    const int pw = t >> 5;
    float fbv = FLT_MAX; int fbi = 0x7fffffff;
#pragma unroll
    for (int wcc = 0; wcc < 4; ++wcc)
#pragma unroll
      for (int hh = 0; hh < 2; ++hh) {
        const int li = (pw * 4 + wcc) * 64 + (t & 31) + hh * 32;
        const float v = ((float*)(LB + WV))[li];
        const int ii = ((int*)(LB + WI))[li];
        if (v < fbv || (v == fbv && ii < fbi)) { fbv = v; fbi = ii; }
      }
    out[OFF_A + n0 + t] = (float)fbi;
    ((int*)(LB + IDX))[t] = fbi;
  }
  __syncthreads();

  // ---- gather emb from exact fp32 W ----
  const int pix = t & 63;
  const int kidx = ((int*)(LB + IDX))[pix];
  for (int d = t >> 6; d < 512; d += 8)
    out[OFF_E + ((size_t)(b * 512 + d)) * 1024 + pixbase + pix] = Wc[(size_t)d * 512 + kidx];
}

// ---------------- decode: conv_transpose (kernel spatially FLIPPED) ---------
__global__ __launch_bounds__(256) void k_decode(const float* __restrict__ dw,
                                                const float* __restrict__ db,
                                                float* out) {
  __shared__ __align__(16) float Qs[32][132];
  __shared__ __align__(16) float Ws3[32][68];
  const int n0 = blockIdx.x * 128;
  const int b = n0 / PIXB, pixbase = n0 % PIXB;
  const int mt = blockIdx.y;
  const int t = threadIdx.x;
  const int pg = t & 31, ck = t >> 5;
  float acc[4][8];
#pragma unroll
  for (int p = 0; p < 4; ++p)
#pragma unroll
    for (int k = 0; k < 8; ++k) acc[p][k] = 0.f;
  for (int dc = 0; dc < 16; ++dc) {
#pragma unroll
    for (int ii = 0; ii < 4; ++ii) {
      const int id = t + ii * 256;
      const int dd = id >> 5, p4 = id & 31;
      *reinterpret_cast<float4*>(&Qs[dd][p4 * 4]) =
        *reinterpret_cast<const float4*>(&out[OFF_E + ((size_t)b * 512 + dc * 32 + dd) * 1024 + pixbase + p4 * 4]);
    }
#pragma unroll
    for (int ii = 0; ii < 2; ++ii) {
      const int id = t + ii * 256;
      const int dd = id >> 4, m4 = id & 15;
      *reinterpret_cast<float4*>(&Ws3[dd][m4 * 4]) =
        *reinterpret_cast<const float4*>(&dw[(size_t)(dc * 32 + dd) * 192 + mt * 64 + m4 * 4]);
    }
    __syncthreads();
#pragma unroll
    for (int dd = 0; dd < 32; ++dd) {
      const float4 qv = *reinterpret_cast<const float4*>(&Qs[dd][pg * 4]);
      const float4 wa = *reinterpret_cast<const float4*>(&Ws3[dd][ck * 8]);
      const float4 wb = *reinterpret_cast<const float4*>(&Ws3[dd][ck * 8 + 4]);
      const float q[4] = {qv.x, qv.y, qv.z, qv.w};
      const float w[8] = {wa.x, wa.y, wa.z, wa.w, wb.x, wb.y, wb.z, wb.w};
#pragma unroll
      for (int p = 0; p < 4; ++p)
#pragma unroll
        for (int k = 0; k < 8; ++k) acc[p][k] = fmaf(q[p], w[k], acc[p][k]);
    }
    __syncthreads();
  }
  const int ckg = mt * 8 + ck;
  const int c = ckg >> 3, ki = ckg & 7;
  const float bias = db[c];
#pragma unroll
  for (int p = 0; p < 4; ++p) {
    const int pix = pixbase + pg * 4 + p;
    const int i = pix >> 5, j = pix & 31;
    const size_t base = (((size_t)b * 3 + c) * 256 + i * 8 + 7 - ki) * 256 + j * 8;
#pragma unroll
    for (int kj = 0; kj < 8; ++kj) out[base + 7 - kj] = acc[p][kj] + bias;
  }
}

extern "C" void kernel_launch(void* const* d_in, const int* in_sizes, int n_in,
                              void* d_out, int out_size, void* d_ws, size_t ws_size,
                              hipStream_t stream) {
  const float* x     = (const float*)d_in[0];
  const float* enc_w = (const float*)d_in[1];
  const float* enc_b = (const float*)d_in[2];
  const float* dec_w = (const float*)d_in[3];
  const float* dec_b = (const float*)d_in[4];
  const float* emb_w = (const float*)d_in[5];
  float* out = (float*)d_out;
  float* w2 = (float*)d_ws;                 // 512 floats
  _Float16* wq = (_Float16*)d_out;          // 1.31MB in recon region (overwritten by k_decode)

  k_prep<<<1282, 256, 0, stream>>>(emb_w, wq, w2);
  k_encode<<<dim3(512, 8), 256, 0, stream>>>(x, enc_w, enc_b, out);
  k_dist<<<512, 512, 0, stream>>>(emb_w, w2, (const _Float16*)d_out, out);
  k_decode<<<dim3(256, 3), 256, 0, stream>>>(dec_w, dec_b, out);
}